// Round 2
// baseline (469.795 us; speedup 1.0000x reference)
//
#include <hip/hip_runtime.h>
#include <hip/hip_cooperative_groups.h>
#include <math.h>

namespace cg = cooperative_groups;

// ---------------------------------------------------------------------------
// HierarchicalVAE, MI355X (gfx950), fp32 — R8: single cooperative kernel.
// R7 post-mortem: dur_us is a cold single-shot graph time; 9 separate stage
// kernels each pay launch gap + cold HBM weight fetch (~190us total).
// R8: one hipLaunchCooperativeKernel (256 blocks x 512 thr = 1 block/CU),
// 8 grid.sync()s instead of 8 launch boundaries; all future-stage weights
// prefetched (L2-warmed) during enc1; XCD-bijective block remap L so each
// XCD reads a contiguous column slice of the big weight matrices.
//
// Output layout (flat f32): rendered@0, mu@100352, logvar@108544,
// cp@116736, widths@124928, alphas@125184.
// ---------------------------------------------------------------------------

#define O_MU  100352
#define O_LV  108544
#define O_CP  116736
#define O_WD  124928
#define O_AL  125184

// workspace float offsets (total 354816 floats = 1.42 MB)
#define W_H1   0        // h1_T  [256][128]
#define W_HE   32768    // he_T  [256][128]
#define W_MUT  65536    // mu_T  [64][128]
#define W_LVT  73728    // lv_T  [64][128]
#define W_D1   81920    // d1_T  [512][128]
#define W_H2   147456   // h2_T  [512][128]
#define W_PN   212992   // pn_T  [28][128]
#define W_R1Z  216576   // r1z_T [512][128] (ref1 z-partials, pre-bias)
#define W_R1   282112   // r1_T  [512][128]
#define W_PT   347648   // P_T   [52][128]
#define W_WA   354304   // wa_T  [4][128]  (w0,w1,a0,a1)

__device__ __forceinline__ float leaky(float x) { return x >= 0.f ? x : 0.2f * x; }
__device__ __forceinline__ float seluf(float x) {
    const float s = 1.0507009873554805f, a = 1.6732632423543772f;
    return x > 0.f ? s * x : s * (a * expm1f(x));
}
__device__ __forceinline__ float sigm(float x) { return 1.f / (1.f + expf(-x)); }

__global__ __launch_bounds__(512)
void vae_coop(const float* __restrict__ x, const float* __restrict__ eps,
              const float* __restrict__ enc_w1, const float* __restrict__ enc_b1,
              const float* __restrict__ enc_w2, const float* __restrict__ enc_b2,
              const float* __restrict__ mu_w, const float* __restrict__ mu_b,
              const float* __restrict__ lv_w, const float* __restrict__ lv_b,
              const float* __restrict__ dec_w1, const float* __restrict__ dec_b1,
              const float* __restrict__ dec_w2, const float* __restrict__ dec_b2,
              const float* __restrict__ cp_w, const float* __restrict__ cp_b,
              const float* __restrict__ ref_w1, const float* __restrict__ ref_b1,
              const float* __restrict__ ref_w2, const float* __restrict__ ref_b2,
              const float* __restrict__ wd_w, const float* __restrict__ wd_b,
              const float* __restrict__ al_w, const float* __restrict__ al_b,
              float* __restrict__ out, float* __restrict__ ws) {
    cg::grid_group grid = cg::this_grid();
    __shared__ float part[4][2][128];   // 4 KB phase scratch
    __shared__ float sP[56];
    __shared__ float sWA[4];
    __shared__ float sQ[128];

    const int b = blockIdx.x;
    const int L = (b & 7) * 32 + (b >> 3);   // bijective: XCD x owns L in [32x,32x+32)
    const int tid = threadIdx.x;
    const int r = tid & 127;                 // batch row
    const int ks = tid >> 7;                 // K-slice 0..3

    float* const h1T  = ws + W_H1;
    float* const heT  = ws + W_HE;
    float* const muT  = ws + W_MUT;
    float* const lvT  = ws + W_LVT;
    float* const d1T  = ws + W_D1;
    float* const h2T  = ws + W_H2;
    float* const pnT  = ws + W_PN;
    float* const r1zT = ws + W_R1Z;
    float* const r1T  = ws + W_R1;
    float* const PT   = ws + W_PT;
    float* const waT  = ws + W_WA;

    // ---- prefetch every later-stage weight line this block will consume.
    // Issued now; consumed (asm) after enc1's main loop -> loads complete
    // in enc1's shadow and the lines are L2-warm for their phase.
    float pf = 0.f;
    {
        const int j0 = 2 * L;
        pf += dec_w2[tid * 512 + j0];                               // phase dec2
        if (tid < 92)  pf += ref_w1[tid * 512 + j0];                // ref1 (both parts)
        if (tid < 64)  pf += dec_w1[tid * 512 + j0];                // dec1
        if (tid < 256) pf += enc_w2[tid * 256 + L];                 // enc2
        if (b < 128 && tid < 256)
            pf += (b >= 64 ? lv_w : mu_w)[tid * 64 + (b & 63)];     // mulv
        if (b < 28)    pf += cp_w[tid * 28 + b];                    // heads
        if (b < 52)    pf += ref_w2[tid * 52 + b];                  // ref2
    }

    // ================= phase 1: enc1 (j = L, K=784, slice 196) =================
    {
        const float* __restrict__ xr = x + r * 784;
        const int k0 = ks * 196;
        float acc = 0.f;
#pragma unroll 4
        for (int i = 0; i < 196; i++)
            acc = fmaf(xr[k0 + i], enc_w1[(k0 + i) * 256 + L], acc);
        asm volatile("" :: "v"(pf));     // consume prefetch AFTER enc1 loads issued
        part[ks][0][r] = acc;
    }
    __syncthreads();
    if (tid < 128) {
        float s = enc_b1[L];
#pragma unroll
        for (int q = 0; q < 4; q++) s += part[q][0][tid];
        h1T[L * 128 + tid] = leaky(s);
    }
    grid.sync();

    // ================= phase 2: enc2 (j = L, K=256, slice 64) ==================
    {
        const int k0 = ks * 64;
        float acc = 0.f;
#pragma unroll 8
        for (int i = 0; i < 64; i++)
            acc = fmaf(h1T[(k0 + i) * 128 + r], enc_w2[(k0 + i) * 256 + L], acc);
        part[ks][0][r] = acc;
    }
    __syncthreads();
    if (tid < 128) {
        float s = enc_b2[L];
#pragma unroll
        for (int q = 0; q < 4; q++) s += part[q][0][tid];
        heT[L * 128 + tid] = leaky(s);
    }
    grid.sync();

    // ================= phase 3: mu|lv (blocks b<128, K=256, slice 64) ==========
    if (b < 128) {
        const int head = b >> 6, col = b & 63;
        const float* __restrict__ w = head ? lv_w : mu_w;
        const int k0 = ks * 64;
        float acc = 0.f;
#pragma unroll 8
        for (int i = 0; i < 64; i++)
            acc = fmaf(heT[(k0 + i) * 128 + r], w[(k0 + i) * 64 + col], acc);
        part[ks][0][r] = acc;
        __syncthreads();
        if (tid < 128) {
            float s = (head ? lv_b : mu_b)[col];
#pragma unroll
            for (int q = 0; q < 4; q++) s += part[q][0][tid];
            (head ? lvT : muT)[col * 128 + tid] = s;
            out[(head ? O_LV : O_MU) + tid * 64 + col] = s;
        }
    }
    grid.sync();

    // ================= phase 4: dec1 (cols 2L,2L+1, K=64, slice 16) ============
    {
        const int j0 = 2 * L, k0 = ks * 16;
        float a0 = 0.f, a1 = 0.f;
#pragma unroll
        for (int i = 0; i < 16; i++) {
            const int k = k0 + i;
            float zv = fmaf(eps[r * 64 + k], expf(0.5f * lvT[k * 128 + r]), muT[k * 128 + r]);
            a0 = fmaf(zv, dec_w1[k * 512 + j0],     a0);
            a1 = fmaf(zv, dec_w1[k * 512 + j0 + 1], a1);
        }
        part[ks][0][r] = a0; part[ks][1][r] = a1;
    }
    __syncthreads();
    if (tid < 256) {
        const int c = tid >> 7, ll = tid & 127;
        float s = dec_b1[2 * L + c];
#pragma unroll
        for (int q = 0; q < 4; q++) s += part[q][c][ll];
        d1T[(2 * L + c) * 128 + ll] = seluf(s);
    }
    grid.sync();

    // ================= phase 5: dec2 (cols 2L,2L+1, K=512, slice 128) ==========
    {
        const int j0 = 2 * L, k0 = ks * 128;
        float a0 = 0.f, a1 = 0.f;
#pragma unroll 4
        for (int i = 0; i < 128; i++) {
            const float v = d1T[(k0 + i) * 128 + r];
            a0 = fmaf(v, dec_w2[(k0 + i) * 512 + j0],     a0);
            a1 = fmaf(v, dec_w2[(k0 + i) * 512 + j0 + 1], a1);
        }
        part[ks][0][r] = a0; part[ks][1][r] = a1;
    }
    __syncthreads();
    if (tid < 256) {
        const int c = tid >> 7, ll = tid & 127;
        float s = dec_b2[2 * L + c];
#pragma unroll
        for (int q = 0; q < 4; q++) s += part[q][c][ll];
        h2T[(2 * L + c) * 128 + ll] = seluf(s);
    }
    grid.sync();

    // ========== phase 6: ref1 z-part (all blocks) + heads (b<32) ==============
    {   // 6a: ref1 partial over k<64 (z recomputed; pn not needed yet)
        const int j0 = 2 * L, k0 = ks * 16;
        float a0 = 0.f, a1 = 0.f;
#pragma unroll
        for (int i = 0; i < 16; i++) {
            const int k = k0 + i;
            float zv = fmaf(eps[r * 64 + k], expf(0.5f * lvT[k * 128 + r]), muT[k * 128 + r]);
            a0 = fmaf(zv, ref_w1[k * 512 + j0],     a0);
            a1 = fmaf(zv, ref_w1[k * 512 + j0 + 1], a1);
        }
        part[ks][0][r] = a0; part[ks][1][r] = a1;
    }
    __syncthreads();
    if (tid < 256) {
        const int c = tid >> 7, ll = tid & 127;
        float s = 0.f;
#pragma unroll
        for (int q = 0; q < 4; q++) s += part[q][c][ll];
        r1zT[(2 * L + c) * 128 + ll] = s;
    }
    __syncthreads();
    if (b < 32) {   // 6b: heads on h2
        const float* __restrict__ w; int ldw, col;
        if (b < 28)      { w = cp_w; ldw = 28; col = b; }
        else if (b < 30) { w = wd_w; ldw = 2;  col = b - 28; }
        else             { w = al_w; ldw = 2;  col = b - 30; }
        const int k0 = ks * 128;
        float acc = 0.f;
#pragma unroll 4
        for (int i = 0; i < 128; i++)
            acc = fmaf(h2T[(k0 + i) * 128 + r], w[(k0 + i) * ldw + col], acc);
        part[ks][0][r] = acc;
        __syncthreads();
        if (tid < 128) {
            float s = 0.f;
#pragma unroll
            for (int q = 0; q < 4; q++) s += part[q][0][tid];
            if (b < 28) {
                pnT[b * 128 + tid] = tanhf(s + cp_b[col]);
            } else if (b < 30) {
                float v = fmaf(sigm(s + wd_b[col]), 2.f, 1.f);
                out[O_WD + tid * 2 + col] = v; waT[col * 128 + tid] = v;
            } else {
                float v = sigm(s + al_b[col]);
                out[O_AL + tid * 2 + col] = v; waT[(2 + col) * 128 + tid] = v;
            }
        }
    }
    grid.sync();

    // ================= phase 7: ref1 pn-part + combine (K=28, slice 7) =========
    {
        const int j0 = 2 * L, k0 = 64 + ks * 7;
        float a0 = 0.f, a1 = 0.f;
#pragma unroll
        for (int i = 0; i < 7; i++) {
            const int k = k0 + i;
            const float v = pnT[(k - 64) * 128 + r];
            a0 = fmaf(v, ref_w1[k * 512 + j0],     a0);
            a1 = fmaf(v, ref_w1[k * 512 + j0 + 1], a1);
        }
        part[ks][0][r] = a0; part[ks][1][r] = a1;
    }
    __syncthreads();
    if (tid < 256) {
        const int c = tid >> 7, ll = tid & 127;
        float s = ref_b1[2 * L + c] + r1zT[(2 * L + c) * 128 + ll];
#pragma unroll
        for (int q = 0; q < 4; q++) s += part[q][c][ll];
        r1T[(2 * L + c) * 128 + ll] = seluf(s);
    }
    grid.sync();

    // ================= phase 8: ref2 (blocks b<52, K=512, slice 128) ===========
    if (b < 52) {
        const int k0 = ks * 128;
        float acc = 0.f;
#pragma unroll 4
        for (int i = 0; i < 128; i++)
            acc = fmaf(r1T[(k0 + i) * 128 + r], ref_w2[(k0 + i) * 52 + b], acc);
        part[ks][0][r] = acc;
        __syncthreads();
        if (tid < 128) {
            float s = ref_b2[b];
#pragma unroll
            for (int q = 0; q < 4; q++) s += part[q][0][tid];
            PT[b * 128 + tid] = fmaf(tanhf(s), 12.f, 14.f);
        }
    }
    grid.sync();

    // ================= phase 9: raster (row = b>>1, half = b&1) ================
    {
        const int row = b >> 1, half = b & 1;
        if (tid < 52) sP[tid] = PT[tid * 128 + row];
        if (tid >= 64 && tid < 68) sWA[tid - 64] = waT[(tid - 64) * 128 + row];
        __syncthreads();
        if (half == 0 && tid < 64) {
            const int idx = tid, p = idx >> 5, rest = idx & 31;
            const int s = rest >> 3, kk = (rest >> 1) & 3, d = idx & 1;
            out[O_CP + row * 64 + idx] = sP[p * 26 + (3 * s + kk) * 2 + d];
        }
        if (tid < 128) {
            const int idx = tid, p = idx >> 6, s = (idx >> 4) & 3, ti = (idx >> 1) & 7, d = idx & 1;
            const float t = (float)ti / 7.0f, mt = 1.0f - t;
            const float c0 = mt * mt * mt, c1 = 3.f * mt * mt * t;
            const float c2 = 3.f * mt * t * t, c3 = t * t * t;
            const float* base = sP + p * 26 + 6 * s + d;
            sQ[idx] = c0 * base[0] + c1 * base[2] + c2 * base[4] + c3 * base[6];
        }
        __syncthreads();
        const float2* __restrict__ sQ2 = (const float2*)sQ;
        for (int u = tid; u < 1568; u += 512) {
            const int pixel = half * 392 + (u >> 2);
            const int sub = u & 3;
            const int py = pixel / 28, px = pixel - py * 28;
            const float sy = ((float)(2 * py + (sub >> 1)) + 0.5f) * 0.5f;
            const float sx = ((float)(2 * px + (sub & 1)) + 0.5f) * 0.5f;
            float img = 1.0f;
#pragma unroll
            for (int p = 0; p < 2; p++) {
                float dmin2 = 1e30f;
                int cnt = 0;
                float2 cur = sQ2[p * 32];
                bool bp = cur.y > sy;
#pragma unroll
                for (int m = 0; m < 32; m++) {
                    float2 nxt = sQ2[p * 32 + ((m + 1) & 31)];
                    float dx = sx - cur.x;
                    float dy = sy - cur.y;
                    dmin2 = fminf(dmin2, fmaf(dx, dx, dy * dy));
                    bool bn = nxt.y > sy;
                    float den = nxt.y - cur.y + 1e-8f;
                    float lhs = dx * den;
                    float rhs = dy * (nxt.x - cur.x);
                    if ((bp != bn) && ((lhs < rhs) == (den > 0.0f))) cnt++;
                    cur = nxt;
                    bp = bn;
                }
                float dist = sqrtf(dmin2);
                float stroke = fminf(fmaxf(fmaf(sWA[p], 0.5f, 0.5f) - dist, 0.f), 1.f);
                float cov = fmaxf((float)(cnt & 1), stroke);
                img *= fmaf(-sWA[2 + p], cov, 1.0f);
            }
            img += __shfl_xor(img, 1);
            img += __shfl_xor(img, 2);
            if (sub == 0) out[row * 784 + pixel] = 1.0f - 0.25f * img;
        }
    }
}

extern "C" void kernel_launch(void* const* d_in, const int* in_sizes, int n_in,
                              void* d_out, int out_size, void* d_ws, size_t ws_size,
                              hipStream_t stream) {
    const float* x      = (const float*)d_in[0];
    const float* eps    = (const float*)d_in[1];
    const float* enc_w1 = (const float*)d_in[2];
    const float* enc_b1 = (const float*)d_in[3];
    const float* enc_w2 = (const float*)d_in[4];
    const float* enc_b2 = (const float*)d_in[5];
    const float* mu_w   = (const float*)d_in[6];
    const float* mu_b   = (const float*)d_in[7];
    const float* lv_w   = (const float*)d_in[8];
    const float* lv_b   = (const float*)d_in[9];
    const float* dec_w1 = (const float*)d_in[10];
    const float* dec_b1 = (const float*)d_in[11];
    const float* dec_w2 = (const float*)d_in[12];
    const float* dec_b2 = (const float*)d_in[13];
    const float* cp_w   = (const float*)d_in[14];
    const float* cp_b   = (const float*)d_in[15];
    const float* ref_w1 = (const float*)d_in[16];
    const float* ref_b1 = (const float*)d_in[17];
    const float* ref_w2 = (const float*)d_in[18];
    const float* ref_b2 = (const float*)d_in[19];
    const float* wd_w   = (const float*)d_in[20];
    const float* wd_b   = (const float*)d_in[21];
    const float* al_w   = (const float*)d_in[22];
    const float* al_b   = (const float*)d_in[23];

    float* out = (float*)d_out;
    float* ws  = (float*)d_ws;   // needs 354816 floats = 1.42 MB

    void* args[] = {
        (void*)&x, (void*)&eps,
        (void*)&enc_w1, (void*)&enc_b1, (void*)&enc_w2, (void*)&enc_b2,
        (void*)&mu_w, (void*)&mu_b, (void*)&lv_w, (void*)&lv_b,
        (void*)&dec_w1, (void*)&dec_b1, (void*)&dec_w2, (void*)&dec_b2,
        (void*)&cp_w, (void*)&cp_b, (void*)&ref_w1, (void*)&ref_b1,
        (void*)&ref_w2, (void*)&ref_b2, (void*)&wd_w, (void*)&wd_b,
        (void*)&al_w, (void*)&al_b, (void*)&out, (void*)&ws
    };
    hipLaunchCooperativeKernel((void*)vae_coop, dim3(256), dim3(512),
                               args, 0, stream);
}

// Round 3
// 190.050 us; speedup vs baseline: 2.4720x; 2.4720x over previous
//
#include <hip/hip_runtime.h>
#include <math.h>

// ---------------------------------------------------------------------------
// HierarchicalVAE, MI355X (gfx950), fp32 — R9: R7 stages + overlapped prefetch.
// R8 post-mortem: cg::grid.sync() costs ~40us each on 8-XCD MI355X (L2
// writeback/inv per sync) -> 8 syncs = 320us, 2.5x regression. Reverted.
// R7 residual analysis: harness fill writes 268MB (> 256MB LLC) between
// iterations -> every iteration is COLD; 9 stages serially re-fetch weights
// from HBM (~15-20us each of latency-chain).
// R9: enc1_k grid 512+256; blocks >=512 stream ALL later-stage weights
// (float4, ~1.9MB) into L2/LLC concurrently with enc1 compute. Stages 2-9
// unchanged from R7 (identical numerics), now hit warm cache.
//
// Output layout (flat f32): rendered@0, mu@100352, logvar@108544,
// cp@116736, widths@124928, alphas@125184.
// ---------------------------------------------------------------------------

#define O_MU  100352
#define O_LV  108544
#define O_CP  116736
#define O_WD  124928
#define O_AL  125184

// workspace float offsets (total 289280 floats = 1.16 MB)
#define W_H1   0        // h1_T  [256][128]
#define W_HE   32768    // he_T  [256][128]
#define W_MUT  65536    // mu_T  [64][128]
#define W_LVT  73728    // lv_T  [64][128]
#define W_D1   81920    // d1_T  [512][128]
#define W_H2   147456   // h2_T  [512][128]
#define W_PN   212992   // pn_T  [28][128]
#define W_R1   216576   // r1_T  [512][128]
#define W_PT   282112   // P_T   [52][128]
#define W_WA   288768   // wa_T  [4][128]  (w0,w1,a0,a1)

__device__ __forceinline__ float leaky(float x) { return x >= 0.f ? x : 0.2f * x; }
__device__ __forceinline__ float seluf(float x) {
    const float s = 1.0507009873554805f, a = 1.6732632423543772f;
    return x > 0.f ? s * x : s * (a * expm1f(x));
}
__device__ __forceinline__ float sigm(float x) { return 1.f / (1.f + expf(-x)); }

// ---- enc1 + prefetch: blocks <512 compute h1_T; blocks >=512 stream all
// later-stage weights into L2/LLC (caches are cold every iteration: the
// harness's 268MB fill evicts the whole LLC between iterations).
__global__ __launch_bounds__(512)
void enc1_k(const float* __restrict__ x, const float* __restrict__ w,
            const float* __restrict__ b, float* __restrict__ outT,
            const float* __restrict__ enc_w2, const float* __restrict__ mu_w,
            const float* __restrict__ lv_w, const float* __restrict__ dec_w1,
            const float* __restrict__ dec_w2, const float* __restrict__ cp_w,
            const float* __restrict__ wd_w, const float* __restrict__ al_w,
            const float* __restrict__ ref_w1, const float* __restrict__ ref_w2,
            const float* __restrict__ eps) {
    if (blockIdx.x >= 512) {
        // ---- prefetch path: 256 blocks x 512 thr = 131072 threads
        const int t = (blockIdx.x - 512) * 512 + threadIdx.x;
        const int NT = 256 * 512;
        float acc = 0.f;
        const float4* p;
        p = (const float4*)dec_w2;  // 65536 f4 (1 MB)
        for (int i = t; i < 65536; i += NT) acc += p[i].x;
        p = (const float4*)enc_w2;  // 16384 f4
        if (t < 16384) acc += p[t].x;
        p = (const float4*)ref_w1;  // 11776 f4
        if (t < 11776) acc += p[t].x;
        p = (const float4*)dec_w1;  // 8192 f4
        if (t < 8192) acc += p[t].x;
        p = (const float4*)ref_w2;  // 6656 f4
        if (t < 6656) acc += p[t].x;
        p = (const float4*)mu_w;    // 4096 f4
        if (t < 4096) acc += p[t].x;
        p = (const float4*)lv_w;    // 4096 f4
        if (t < 4096) acc += p[t].x;
        p = (const float4*)cp_w;    // 3584 f4
        if (t < 3584) acc += p[t].x;
        p = (const float4*)eps;     // 2048 f4
        if (t < 2048) acc += p[t].x;
        if (t < 256) acc += ((const float4*)wd_w)[t].x;
        if (t < 256) acc += ((const float4*)al_w)[t].x;
        asm volatile("" :: "v"(acc));   // keep loads live, no store
        return;
    }
    __shared__ float part[8][64];
    const int j = blockIdx.x >> 1, h = blockIdx.x & 1;
    const int tid = threadIdx.x, lane = tid & 63, ks = tid >> 6;
    const int r = h * 64 + lane;
    const float* __restrict__ xr = x + r * 784;
    float acc = 0.f;
    const int k0 = ks * 98;
#pragma unroll 7
    for (int i = 0; i < 98; i++)
        acc = fmaf(xr[k0 + i], w[(k0 + i) * 256 + j], acc);
    part[ks][lane] = acc;
    __syncthreads();
    if (tid < 64) {
        float s = b[j];
#pragma unroll
        for (int q = 0; q < 8; q++) s += part[q][tid];
        outT[j * 128 + h * 64 + tid] = leaky(s);
    }
}

// ---- enc2: he_T = leaky(h1_T^T @ enc_w2 + b). grid 512.
__global__ __launch_bounds__(512)
void enc2_k(const float* __restrict__ inT, const float* __restrict__ w,
            const float* __restrict__ b, float* __restrict__ outT) {
    __shared__ float part[8][64];
    const int j = blockIdx.x >> 1, h = blockIdx.x & 1;
    const int tid = threadIdx.x, lane = tid & 63, ks = tid >> 6;
    const int r = h * 64 + lane;
    float acc = 0.f;
    const int k0 = ks * 32;
#pragma unroll 8
    for (int i = 0; i < 32; i++)
        acc = fmaf(inT[(k0 + i) * 128 + r], w[(k0 + i) * 256 + j], acc);
    part[ks][lane] = acc;
    __syncthreads();
    if (tid < 64) {
        float s = b[j];
#pragma unroll
        for (int q = 0; q < 8; q++) s += part[q][tid];
        outT[j * 128 + h * 64 + tid] = leaky(s);
    }
}

// ---- mu|lv: grid 256: meta=bid>>1 (head=meta>>6, col=meta&63), h=bid&1.
__global__ __launch_bounds__(512)
void mulv_k(const float* __restrict__ heT,
            const float* __restrict__ mu_w, const float* __restrict__ mu_b,
            const float* __restrict__ lv_w, const float* __restrict__ lv_b,
            float* __restrict__ muT, float* __restrict__ lvT,
            float* __restrict__ out) {
    __shared__ float part[8][64];
    const int meta = blockIdx.x >> 1, h = blockIdx.x & 1;
    const int head = meta >> 6, col = meta & 63;
    const float* __restrict__ w = head ? lv_w : mu_w;
    const int tid = threadIdx.x, lane = tid & 63, ks = tid >> 6;
    const int r = h * 64 + lane;
    float acc = 0.f;
    const int k0 = ks * 32;
#pragma unroll 8
    for (int i = 0; i < 32; i++)
        acc = fmaf(heT[(k0 + i) * 128 + r], w[(k0 + i) * 64 + col], acc);
    part[ks][lane] = acc;
    __syncthreads();
    if (tid < 64) {
        float s = (head ? lv_b : mu_b)[col];
#pragma unroll
        for (int q = 0; q < 16 / 2; q++) s += part[q][tid];
        const int rr = h * 64 + tid;
        (head ? lvT : muT)[col * 128 + rr] = s;
        out[(head ? O_LV : O_MU) + rr * 64 + col] = s;
    }
}

// ---- dec1: d1_T = selu(z @ dec_w1 + b), z recomputed from mu/lv/eps.
// grid 512: jpair=bid>>1 (2 cols), h=bid&1. slice 8.
__global__ __launch_bounds__(512)
void dec1_k(const float* __restrict__ muT, const float* __restrict__ lvT,
            const float* __restrict__ eps, const float* __restrict__ w,
            const float* __restrict__ b, float* __restrict__ outT) {
    __shared__ float part[8][2][64];
    const int j0 = (blockIdx.x >> 1) * 2, h = blockIdx.x & 1;
    const int tid = threadIdx.x, lane = tid & 63, ks = tid >> 6;
    const int r = h * 64 + lane;
    float a0 = 0.f, a1 = 0.f;
    const int k0 = ks * 8;
#pragma unroll
    for (int i = 0; i < 8; i++) {
        const int k = k0 + i;
        float zv = fmaf(eps[r * 64 + k], expf(0.5f * lvT[k * 128 + r]), muT[k * 128 + r]);
        a0 = fmaf(zv, w[k * 512 + j0],     a0);
        a1 = fmaf(zv, w[k * 512 + j0 + 1], a1);
    }
    part[ks][0][lane] = a0; part[ks][1][lane] = a1;
    __syncthreads();
    if (tid < 128) {
        const int c = tid >> 6, ll = tid & 63;
        float s = b[j0 + c];
#pragma unroll
        for (int q = 0; q < 8; q++) s += part[q][c][ll];
        outT[(j0 + c) * 128 + h * 64 + ll] = seluf(s);
    }
}

// ---- dec2: h2_T = selu(d1 @ dec_w2 + b). grid 512, 2 cols, slice 64.
__global__ __launch_bounds__(512)
void dec2_k(const float* __restrict__ inT, const float* __restrict__ w,
            const float* __restrict__ b, float* __restrict__ outT) {
    __shared__ float part[8][2][64];
    const int j0 = (blockIdx.x >> 1) * 2, h = blockIdx.x & 1;
    const int tid = threadIdx.x, lane = tid & 63, ks = tid >> 6;
    const int r = h * 64 + lane;
    float a0 = 0.f, a1 = 0.f;
    const int k0 = ks * 64;
#pragma unroll 4
    for (int i = 0; i < 64; i++) {
        const float v = inT[(k0 + i) * 128 + r];
        a0 = fmaf(v, w[(k0 + i) * 512 + j0],     a0);
        a1 = fmaf(v, w[(k0 + i) * 512 + j0 + 1], a1);
    }
    part[ks][0][lane] = a0; part[ks][1][lane] = a1;
    __syncthreads();
    if (tid < 128) {
        const int c = tid >> 6, ll = tid & 63;
        float s = b[j0 + c];
#pragma unroll
        for (int q = 0; q < 8; q++) s += part[q][c][ll];
        outT[(j0 + c) * 128 + h * 64 + ll] = seluf(s);
    }
}

// ---- heads: cp->pn_T (tanh), wd/al->out + wa_T. grid 64: j=bid>>1, h=bid&1.
__global__ __launch_bounds__(512)
void heads_k(const float* __restrict__ h2T,
             const float* __restrict__ cp_w, const float* __restrict__ cp_b,
             const float* __restrict__ wd_w, const float* __restrict__ wd_b,
             const float* __restrict__ al_w, const float* __restrict__ al_b,
             float* __restrict__ pnT, float* __restrict__ waT,
             float* __restrict__ out) {
    __shared__ float part[8][64];
    const int j = blockIdx.x >> 1, h = blockIdx.x & 1;
    const float* __restrict__ w; int ldw, col;
    if (j < 28)      { w = cp_w; ldw = 28; col = j; }
    else if (j < 30) { w = wd_w; ldw = 2;  col = j - 28; }
    else             { w = al_w; ldw = 2;  col = j - 30; }
    const int tid = threadIdx.x, lane = tid & 63, ks = tid >> 6;
    const int r = h * 64 + lane;
    float acc = 0.f;
    const int k0 = ks * 64;
#pragma unroll 8
    for (int i = 0; i < 64; i++)
        acc = fmaf(h2T[(k0 + i) * 128 + r], w[(k0 + i) * ldw + col], acc);
    part[ks][lane] = acc;
    __syncthreads();
    if (tid < 64) {
        float s = 0.f;
#pragma unroll
        for (int q = 0; q < 8; q++) s += part[q][tid];
        const int rr = h * 64 + tid;
        if (j < 28) {
            pnT[j * 128 + rr] = tanhf(s + cp_b[col]);
        } else if (j < 30) {
            float v = fmaf(sigm(s + wd_b[col]), 2.f, 1.f);
            out[O_WD + rr * 2 + col] = v; waT[col * 128 + rr] = v;
        } else {
            float v = sigm(s + al_b[col]);
            out[O_AL + rr * 2 + col] = v; waT[(2 + col) * 128 + rr] = v;
        }
    }
}

// ---- ref1: r1_T = selu(h_in @ ref_w1 + b); h_in = [z(64) | pn(28)].
// grid 512, 2 cols, slice 12 (guard k<92).
__global__ __launch_bounds__(512)
void ref1_k(const float* __restrict__ muT, const float* __restrict__ lvT,
            const float* __restrict__ eps, const float* __restrict__ pnT,
            const float* __restrict__ w, const float* __restrict__ b,
            float* __restrict__ outT) {
    __shared__ float part[8][2][64];
    const int j0 = (blockIdx.x >> 1) * 2, h = blockIdx.x & 1;
    const int tid = threadIdx.x, lane = tid & 63, ks = tid >> 6;
    const int r = h * 64 + lane;
    float a0 = 0.f, a1 = 0.f;
#pragma unroll
    for (int i = 0; i < 12; i++) {
        const int k = ks * 12 + i;
        if (k < 92) {
            float v = (k < 64)
                ? fmaf(eps[r * 64 + k], expf(0.5f * lvT[k * 128 + r]), muT[k * 128 + r])
                : pnT[(k - 64) * 128 + r];
            a0 = fmaf(v, w[k * 512 + j0],     a0);
            a1 = fmaf(v, w[k * 512 + j0 + 1], a1);
        }
    }
    part[ks][0][lane] = a0; part[ks][1][lane] = a1;
    __syncthreads();
    if (tid < 128) {
        const int c = tid >> 6, ll = tid & 63;
        float s = b[j0 + c];
#pragma unroll
        for (int q = 0; q < 8; q++) s += part[q][c][ll];
        outT[(j0 + c) * 128 + h * 64 + ll] = seluf(s);
    }
}

// ---- ref2: P_T = tanh(r1 @ ref_w2 + b)*12 + 14. grid 104: j=bid>>1, h=bid&1.
__global__ __launch_bounds__(512)
void ref2_k(const float* __restrict__ r1T, const float* __restrict__ w,
            const float* __restrict__ b, float* __restrict__ PT) {
    __shared__ float part[8][64];
    const int j = blockIdx.x >> 1, h = blockIdx.x & 1;
    const int tid = threadIdx.x, lane = tid & 63, ks = tid >> 6;
    const int r = h * 64 + lane;
    float acc = 0.f;
    const int k0 = ks * 64;
#pragma unroll 8
    for (int i = 0; i < 64; i++)
        acc = fmaf(r1T[(k0 + i) * 128 + r], w[(k0 + i) * 52 + j], acc);
    part[ks][lane] = acc;
    __syncthreads();
    if (tid < 64) {
        float s = b[j];
#pragma unroll
        for (int q = 0; q < 8; q++) s += part[q][tid];
        PT[j * 128 + h * 64 + tid] = fmaf(tanhf(s), 12.f, 14.f);
    }
}

// ---- raster: grid 896 = 128 rows x 7 pixel-chunks (112 px x 4 AA each).
__global__ __launch_bounds__(512)
void raster_k(const float* __restrict__ PT, const float* __restrict__ waT,
              float* __restrict__ out) {
    __shared__ float sP[56];
    __shared__ float sWA[4];
    __shared__ float sQ[128];
    const int bid = blockIdx.x;
    const int row = bid / 7, chunk = bid - row * 7;
    const int tid = threadIdx.x;
    if (tid < 52) sP[tid] = PT[tid * 128 + row];
    if (tid >= 64 && tid < 68) sWA[tid - 64] = waT[(tid - 64) * 128 + row];
    __syncthreads();
    if (chunk == 0 && tid < 64) {
        const int idx = tid, p = idx >> 5, rest = idx & 31;
        const int s = rest >> 3, kk = (rest >> 1) & 3, d = idx & 1;
        out[O_CP + row * 64 + idx] = sP[p * 26 + (3 * s + kk) * 2 + d];
    }
    if (tid < 128) {
        const int idx = tid, p = idx >> 6, s = (idx >> 4) & 3, ti = (idx >> 1) & 7, d = idx & 1;
        const float t = (float)ti / 7.0f, mt = 1.0f - t;
        const float c0 = mt * mt * mt, c1 = 3.f * mt * mt * t;
        const float c2 = 3.f * mt * t * t, c3 = t * t * t;
        const float* base = sP + p * 26 + 6 * s + d;
        sQ[idx] = c0 * base[0] + c1 * base[2] + c2 * base[4] + c3 * base[6];
    }
    __syncthreads();
    if (tid < 448) {
        const int pixel = chunk * 112 + (tid >> 2), sub = tid & 3;
        const int py = pixel / 28, px = pixel - py * 28;
        const float sy = ((float)(2 * py + (sub >> 1)) + 0.5f) * 0.5f;
        const float sx = ((float)(2 * px + (sub & 1)) + 0.5f) * 0.5f;
        const float2* __restrict__ sQ2 = (const float2*)sQ;
        float img = 1.0f;
#pragma unroll
        for (int p = 0; p < 2; p++) {
            float dmin2 = 1e30f;
            int cnt = 0;
            float2 cur = sQ2[p * 32];
            bool bp = cur.y > sy;
#pragma unroll
            for (int m = 0; m < 32; m++) {
                float2 nxt = sQ2[p * 32 + ((m + 1) & 31)];
                float dx = sx - cur.x;
                float dy = sy - cur.y;
                dmin2 = fminf(dmin2, fmaf(dx, dx, dy * dy));
                bool bn = nxt.y > sy;
                float den = nxt.y - cur.y + 1e-8f;
                float lhs = dx * den;
                float rhs = dy * (nxt.x - cur.x);
                if ((bp != bn) && ((lhs < rhs) == (den > 0.0f))) cnt++;
                cur = nxt;
                bp = bn;
            }
            float dist = sqrtf(dmin2);
            float stroke = fminf(fmaxf(fmaf(sWA[p], 0.5f, 0.5f) - dist, 0.f), 1.f);
            float cov = fmaxf((float)(cnt & 1), stroke);
            img *= fmaf(-sWA[2 + p], cov, 1.0f);
        }
        img += __shfl_xor(img, 1);
        img += __shfl_xor(img, 2);
        if (sub == 0) out[row * 784 + pixel] = 1.0f - 0.25f * img;
    }
}

extern "C" void kernel_launch(void* const* d_in, const int* in_sizes, int n_in,
                              void* d_out, int out_size, void* d_ws, size_t ws_size,
                              hipStream_t stream) {
    const float* x      = (const float*)d_in[0];
    const float* eps    = (const float*)d_in[1];
    const float* enc_w1 = (const float*)d_in[2];
    const float* enc_b1 = (const float*)d_in[3];
    const float* enc_w2 = (const float*)d_in[4];
    const float* enc_b2 = (const float*)d_in[5];
    const float* mu_w   = (const float*)d_in[6];
    const float* mu_b   = (const float*)d_in[7];
    const float* lv_w   = (const float*)d_in[8];
    const float* lv_b   = (const float*)d_in[9];
    const float* dec_w1 = (const float*)d_in[10];
    const float* dec_b1 = (const float*)d_in[11];
    const float* dec_w2 = (const float*)d_in[12];
    const float* dec_b2 = (const float*)d_in[13];
    const float* cp_w   = (const float*)d_in[14];
    const float* cp_b   = (const float*)d_in[15];
    const float* ref_w1 = (const float*)d_in[16];
    const float* ref_b1 = (const float*)d_in[17];
    const float* ref_w2 = (const float*)d_in[18];
    const float* ref_b2 = (const float*)d_in[19];
    const float* wd_w   = (const float*)d_in[20];
    const float* wd_b   = (const float*)d_in[21];
    const float* al_w   = (const float*)d_in[22];
    const float* al_b   = (const float*)d_in[23];

    float* out = (float*)d_out;
    float* ws  = (float*)d_ws;   // needs 289280 floats = 1.16 MB

    enc1_k <<<768, 512, 0, stream>>>(x, enc_w1, enc_b1, ws + W_H1,
                                     enc_w2, mu_w, lv_w, dec_w1, dec_w2,
                                     cp_w, wd_w, al_w, ref_w1, ref_w2, eps);
    enc2_k <<<512, 512, 0, stream>>>(ws + W_H1, enc_w2, enc_b2, ws + W_HE);
    mulv_k <<<256, 512, 0, stream>>>(ws + W_HE, mu_w, mu_b, lv_w, lv_b,
                                     ws + W_MUT, ws + W_LVT, out);
    dec1_k <<<512, 512, 0, stream>>>(ws + W_MUT, ws + W_LVT, eps,
                                     dec_w1, dec_b1, ws + W_D1);
    dec2_k <<<512, 512, 0, stream>>>(ws + W_D1, dec_w2, dec_b2, ws + W_H2);
    heads_k<<<64, 512, 0, stream>>>(ws + W_H2, cp_w, cp_b, wd_w, wd_b, al_w, al_b,
                                    ws + W_PN, ws + W_WA, out);
    ref1_k <<<512, 512, 0, stream>>>(ws + W_MUT, ws + W_LVT, eps, ws + W_PN,
                                     ref_w1, ref_b1, ws + W_R1);
    ref2_k <<<104, 512, 0, stream>>>(ws + W_R1, ref_w2, ref_b2, ws + W_PT);
    raster_k<<<896, 512, 0, stream>>>(ws + W_PT, ws + W_WA, out);
}